// Round 1
// baseline (75.032 us; speedup 1.0000x reference)
//
#include <hip/hip_runtime.h>
#include <math.h>

// CausalityMatrix: B=4, M=64, K=14*14=196
// out[b,m,n] = nan0( nan0( (s0[m]*s0[n])/(s1[m]*s1[n]) ) / nan0( t0[n]/t1[n] ) )
// where s0=sum x^p_num, s1=sum x^(p_num-1), t0=sum x^p_den, t1=sum x^(p_den-1)
// over the K spatial elements of row (b,m), with x==0 replaced by 1e-9.

#define BB 4
#define MM 64
#define KK 196

__global__ __launch_bounds__(256) void causality_kernel(
    const float* __restrict__ x,
    const float* __restrict__ p_num_p,
    const float* __restrict__ p_den_p,
    float* __restrict__ out)
{
    __shared__ float s0[MM], s1[MM], t0[MM], t1[MM];

    const int b = blockIdx.x;
    const int t = threadIdx.x;
    const float p_num = p_num_p[0];
    const float p_den = p_den_p[0];

    // ---- phase 1: per-row power sums. 4 threads per row, 49 elems each. ----
    const int m   = t >> 2;   // 0..63
    const int sub = t & 3;    // 0..3
    const float* row = x + ((size_t)b * MM + m) * KK;

    float a0 = 0.f, a1 = 0.f, c0 = 0.f, c1 = 0.f;
    const int k0 = sub * 49;
    #pragma unroll 7
    for (int k = k0; k < k0 + 49; ++k) {
        float v = row[k];
        if (v == 0.0f) v = 1e-9f;
        a0 += powf(v, p_num);
        a1 += powf(v, p_num - 1.0f);
        c0 += powf(v, p_den);
        c1 += powf(v, p_den - 1.0f);
    }
    // reduce the 4 sub-lanes (they are consecutive lanes within a wave)
    a0 += __shfl_xor(a0, 1); a0 += __shfl_xor(a0, 2);
    a1 += __shfl_xor(a1, 1); a1 += __shfl_xor(a1, 2);
    c0 += __shfl_xor(c0, 1); c0 += __shfl_xor(c0, 2);
    c1 += __shfl_xor(c1, 1); c1 += __shfl_xor(c1, 2);
    if (sub == 0) { s0[m] = a0; s1[m] = a1; t0[m] = c0; t1[m] = c1; }
    __syncthreads();

    // ---- phase 2: 64x64 outputs for this b, 16 per thread ----
    float* outb = out + (size_t)b * MM * MM;
    #pragma unroll
    for (int k = 0; k < 16; ++k) {
        const int o  = t + 256 * k;
        const int mi = o >> 6;    // broadcast within a wave-iteration
        const int ni = o & 63;    // stride-1 across lanes
        float num = (s0[mi] * s0[ni]) / (s1[mi] * s1[ni]);
        if (isnan(num)) num = 0.0f;
        float den = t0[ni] / t1[ni];
        if (isnan(den)) den = 0.0f;
        float c = num / den;
        if (isnan(c)) c = 0.0f;
        outb[o] = c;
    }
}

extern "C" void kernel_launch(void* const* d_in, const int* in_sizes, int n_in,
                              void* d_out, int out_size, void* d_ws, size_t ws_size,
                              hipStream_t stream) {
    const float* x     = (const float*)d_in[0];
    const float* p_num = (const float*)d_in[1];
    const float* p_den = (const float*)d_in[2];
    float* out = (float*)d_out;

    causality_kernel<<<BB, 256, 0, stream>>>(x, p_num, p_den, out);
}

// Round 2
// 10.064 us; speedup vs baseline: 7.4557x; 7.4557x over previous
//
#include <hip/hip_runtime.h>
#include <math.h>

// CausalityMatrix: B=4, M=64, K=14*14=196
// out[b,m,n] = nan0( nan0( (s0[m]*s0[n])/(s1[m]*s1[n]) ) / nan0( t0[n]/t1[n] ) )
// s0=sum x^p_num, s1=sum x^(p_num-1), t0=sum x^p_den, t1=sum x^(p_den-1)
// over K spatial elems of row (b,m), with x==0 replaced by 1e-9.
//
// All x > 0, so x^p = exp2(p * log2(x)) via raw v_log_f32 / v_exp_f32.

#define BB 4
#define MM 64
#define KK 196

__global__ __launch_bounds__(1024) void causality_kernel(
    const float* __restrict__ x,
    const float* __restrict__ p_num_p,
    const float* __restrict__ p_den_p,
    float* __restrict__ out)
{
    __shared__ float s0[MM], s1[MM], t0[MM], t1[MM];

    const int b = blockIdx.x;
    const int t = threadIdx.x;
    const float pn  = p_num_p[0];
    const float pn1 = pn - 1.0f;
    const float pd  = p_den_p[0];
    const float pd1 = pd - 1.0f;

    // ---- phase 1: per-row power sums. 16 threads per row, stride-16. ----
    const int m   = t >> 4;   // 0..63
    const int sub = t & 15;   // 0..15
    const float* row = x + ((size_t)b * MM + m) * KK;

    float a0 = 0.f, a1 = 0.f, c0 = 0.f, c1 = 0.f;
    for (int k = sub; k < KK; k += 16) {
        float v = row[k];
        if (v == 0.0f) v = 1e-9f;
        float l = __builtin_amdgcn_logf(v);       // log2(v)
        a0 += __builtin_amdgcn_exp2f(pn  * l);
        a1 += __builtin_amdgcn_exp2f(pn1 * l);
        c0 += __builtin_amdgcn_exp2f(pd  * l);
        c1 += __builtin_amdgcn_exp2f(pd1 * l);
    }
    // reduce across the 16 sub-lanes (contiguous within a 64-lane wave)
    #pragma unroll
    for (int d = 1; d < 16; d <<= 1) {
        a0 += __shfl_xor(a0, d);
        a1 += __shfl_xor(a1, d);
        c0 += __shfl_xor(c0, d);
        c1 += __shfl_xor(c1, d);
    }
    if (sub == 0) { s0[m] = a0; s1[m] = a1; t0[m] = c0; t1[m] = c1; }
    __syncthreads();

    // ---- phase 2: 64x64 outputs for this b, 4 per thread ----
    float* outb = out + (size_t)b * MM * MM;
    #pragma unroll
    for (int k = 0; k < 4; ++k) {
        const int o  = t + 1024 * k;
        const int mi = o >> 6;    // wave-uniform per iteration
        const int ni = o & 63;    // stride-1 across lanes
        float num = (s0[mi] * s0[ni]) / (s1[mi] * s1[ni]);
        if (isnan(num)) num = 0.0f;
        float den = t0[ni] / t1[ni];
        if (isnan(den)) den = 0.0f;
        float c = num / den;
        if (isnan(c)) c = 0.0f;
        outb[o] = c;
    }
}

extern "C" void kernel_launch(void* const* d_in, const int* in_sizes, int n_in,
                              void* d_out, int out_size, void* d_ws, size_t ws_size,
                              hipStream_t stream) {
    const float* x     = (const float*)d_in[0];
    const float* p_num = (const float*)d_in[1];
    const float* p_den = (const float*)d_in[2];
    float* out = (float*)d_out;

    causality_kernel<<<BB, 1024, 0, stream>>>(x, p_num, p_den, out);
}

// Round 3
// 9.753 us; speedup vs baseline: 7.6933x; 1.0319x over previous
//
#include <hip/hip_runtime.h>
#include <math.h>

// CausalityMatrix: B=4, M=64, K=14*14=196
// out[b,m,n] = nan0( nan0( (s0[m]*s0[n])/(s1[m]*s1[n]) ) / nan0( t0[n]/t1[n] ) )
// s0=sum x^p_num, s1=sum x^(p_num-1), t0=sum x^p_den, t1=sum x^(p_den-1)
// over K spatial elems of row (b,m), with x==0 replaced by 1e-9.
//
// Phase 1 latency fix: each row = 49 float4 (rows are 784B, 16B-aligned).
// 16 threads/row issue 3-4 unrolled vector loads -> single latency round trip.
// p==0 fast path: x^0 = 1 exactly, x^-1 via v_rcp_f32 (1 trans op/elem vs 5).

#define BB 4
#define MM 64
#define KK 196

__global__ __launch_bounds__(1024) void causality_kernel(
    const float* __restrict__ x,
    const float* __restrict__ p_num_p,
    const float* __restrict__ p_den_p,
    float* __restrict__ out)
{
    __shared__ float s0[MM], s1[MM], t0[MM], t1[MM];

    const int b = blockIdx.x;
    const int t = threadIdx.x;
    const float pn = p_num_p[0];
    const float pd = p_den_p[0];

    const int m   = t >> 4;   // 0..63  (16 consecutive threads per row)
    const int sub = t & 15;   // 0..15
    const float4* row4 = (const float4*)(x + ((size_t)b * MM + m) * KK);

    // ---- prefetch: 49 float4/row; lane sub takes {sub, sub+16, sub+32},
    //      lane 0 additionally takes #48. All loads issued up front. ----
    float4 w0 = row4[sub];
    float4 w1 = row4[sub + 16];
    float4 w2 = row4[sub + 32];
    float4 w3 = (sub == 0) ? row4[48] : float4{1.f, 1.f, 1.f, 1.f};
    const float m3 = (sub == 0) ? 1.f : 0.f;   // mask for the tail vec4

    auto fix = [](float v) { return v == 0.0f ? 1e-9f : v; };

    float a0, a1, c0, c1;
    if (pn == 0.0f && pd == 0.0f) {
        // fast path: s0 = count (exact), s1 = sum 1/x
        auto r4 = [&](const float4& w) {
            return __builtin_amdgcn_rcpf(fix(w.x)) + __builtin_amdgcn_rcpf(fix(w.y))
                 + __builtin_amdgcn_rcpf(fix(w.z)) + __builtin_amdgcn_rcpf(fix(w.w));
        };
        float r = r4(w0) + r4(w1) + r4(w2) + m3 * r4(w3);
        a0 = c0 = 12.f + 4.f * m3;
        a1 = c1 = r;
    } else {
        // general path: x^p = exp2(p * log2(x)), x > 0
        a0 = a1 = c0 = c1 = 0.f;
        const float pn1 = pn - 1.0f, pd1 = pd - 1.0f;
        auto acc = [&](float v, float msk) {
            float l = __builtin_amdgcn_logf(fix(v));
            a0 += msk * __builtin_amdgcn_exp2f(pn  * l);
            a1 += msk * __builtin_amdgcn_exp2f(pn1 * l);
            c0 += msk * __builtin_amdgcn_exp2f(pd  * l);
            c1 += msk * __builtin_amdgcn_exp2f(pd1 * l);
        };
        auto acc4 = [&](const float4& w, float msk) {
            acc(w.x, msk); acc(w.y, msk); acc(w.z, msk); acc(w.w, msk);
        };
        acc4(w0, 1.f); acc4(w1, 1.f); acc4(w2, 1.f); acc4(w3, m3);
    }

    // ---- reduce across the 16 sub-lanes (contiguous within a wave) ----
    #pragma unroll
    for (int d = 1; d < 16; d <<= 1) {
        a0 += __shfl_xor(a0, d);
        a1 += __shfl_xor(a1, d);
        c0 += __shfl_xor(c0, d);
        c1 += __shfl_xor(c1, d);
    }
    if (sub == 0) { s0[m] = a0; s1[m] = a1; t0[m] = c0; t1[m] = c1; }
    __syncthreads();

    // ---- phase 2: 64x64 outputs for this b, 4 per thread ----
    float* outb = out + (size_t)b * MM * MM;
    #pragma unroll
    for (int k = 0; k < 4; ++k) {
        const int o  = t + 1024 * k;
        const int mi = o >> 6;    // wave-uniform per iteration
        const int ni = o & 63;    // stride-1 across lanes
        float num = (s0[mi] * s0[ni]) / (s1[mi] * s1[ni]);
        if (isnan(num)) num = 0.0f;
        float den = t0[ni] / t1[ni];
        if (isnan(den)) den = 0.0f;
        float c = num / den;
        if (isnan(c)) c = 0.0f;
        outb[o] = c;
    }
}

extern "C" void kernel_launch(void* const* d_in, const int* in_sizes, int n_in,
                              void* d_out, int out_size, void* d_ws, size_t ws_size,
                              hipStream_t stream) {
    const float* x     = (const float*)d_in[0];
    const float* p_num = (const float*)d_in[1];
    const float* p_den = (const float*)d_in[2];
    float* out = (float*)d_out;

    causality_kernel<<<BB, 1024, 0, stream>>>(x, p_num, p_den, out);
}